// Round 1
// baseline (438.292 us; speedup 1.0000x reference)
//
#include <hip/hip_runtime.h>

#define NUM_NODES 100000
#define NUM_EDGES 400000
#define F_IN 16
#define F_EDGE 8
#define EMB 16
#define NUM_GRAPHS 256

// ---------------------------------------------------------------------------
// Workspace layout (all zero-initialized by hipMemsetAsync each launch):
//   sums  : NUM_NODES*EMB  f32   (scatter-sum of edge messages)
//   cnt   : NUM_NODES      f32   (incoming-edge counts)
//   gmax  : NUM_GRAPHS*EMB u32   (float bits; h>=0 so uint max == float max, id=0)
//   gsum  : NUM_GRAPHS*EMB f32
//   gcnt  : NUM_GRAPHS     f32
// ---------------------------------------------------------------------------

// One block = 16 edges x 16 output channels. Thread (eL, o) computes
// msg[e][o] = sum_i x[src[e]][i] * relu(b[i*16+o] + sum_k ea[e][k]*W[(i*16+o)][k])
__global__ __launch_bounds__(256) void edge_kernel(
    const float* __restrict__ x, const int* __restrict__ ei,
    const float* __restrict__ ea, const float* __restrict__ nn1_w,
    const float* __restrict__ nn1_b, float* __restrict__ sums,
    float* __restrict__ cnt)
{
    __shared__ float wt[F_IN * EMB * F_EDGE];  // straight copy of nn1_w (2048 f32, 8 KB)
    __shared__ float bt[EMB * F_IN];           // bt[o*16+i] = nn1_b[i*16+o]
    __shared__ float xs[16 * F_IN];            // x rows for this block's 16 edges
    __shared__ float eas[16 * F_EDGE];         // edge_attr rows

    const int tid = threadIdx.x;
    const int eL  = tid >> 4;
    const int o   = tid & 15;
    const int e   = blockIdx.x * 16 + eL;      // grid is exact: 400000/16 = 25000

    // stage weights
    #pragma unroll
    for (int t = tid; t < F_IN * EMB * F_EDGE; t += 256) wt[t] = nn1_w[t];
    {   // bias transposed so each thread later reads a contiguous 16-float row
        int i = tid >> 4, oo = tid & 15;
        bt[oo * 16 + i] = nn1_b[tid];          // tid = i*16+oo
    }

    const int src = ei[e];
    const int dst = ei[NUM_EDGES + e];

    // stage x[src] (each thread loads one feature) and edge_attr
    xs[eL * 16 + o] = x[src * 16 + o];
    if (o < F_EDGE) eas[eL * F_EDGE + o] = ea[e * F_EDGE + o];
    __syncthreads();

    const float4 ea0 = *(const float4*)&eas[eL * F_EDGE];
    const float4 ea1 = *(const float4*)&eas[eL * F_EDGE + 4];

    float xr[F_IN];
    #pragma unroll
    for (int i = 0; i < F_IN; i++) xr[i] = xs[eL * 16 + i];
    float br[F_IN];
    #pragma unroll
    for (int i = 0; i < F_IN; i++) br[i] = bt[o * 16 + i];

    float acc = 0.f;
    #pragma unroll
    for (int i = 0; i < F_IN; i++) {
        const float4* wr = (const float4*)&wt[(i * 16 + o) * F_EDGE];
        const float4 w0 = wr[0];
        const float4 w1 = wr[1];
        float w = br[i];
        w = fmaf(ea0.x, w0.x, w); w = fmaf(ea0.y, w0.y, w);
        w = fmaf(ea0.z, w0.z, w); w = fmaf(ea0.w, w0.w, w);
        w = fmaf(ea1.x, w1.x, w); w = fmaf(ea1.y, w1.y, w);
        w = fmaf(ea1.z, w1.z, w); w = fmaf(ea1.w, w1.w, w);
        w = fmaxf(w, 0.f);
        acc = fmaf(xr[i], w, acc);
    }

    atomicAdd(&sums[dst * 16 + o], acc);
    if (o == 0) atomicAdd(&cnt[dst], 1.f);
}

// One thread per (node, channel). Block covers 16 nodes.
__global__ __launch_bounds__(256) void node_kernel(
    const float* __restrict__ x, const int* __restrict__ batch,
    const float* __restrict__ root_w, const float* __restrict__ conv_b,
    const float* __restrict__ sums, const float* __restrict__ cnt,
    unsigned int* __restrict__ gmax, float* __restrict__ gsum,
    float* __restrict__ gcnt)
{
    __shared__ float rw[EMB * F_IN];   // root_w as-is: rw[o*16+i]
    __shared__ float xsh[256];         // this block's 16 nodes x 16 features

    const int tid = threadIdx.x;
    rw[tid] = root_w[tid];
    const int g = blockIdx.x * 256 + tid;   // grid exact: 1,600,000/256 = 6250
    xsh[tid] = x[g];                        // coalesced: x rows for nodes of block
    __syncthreads();

    const int n  = g >> 4;
    const int o  = g & 15;
    const int ln = tid >> 4;           // local node

    const float c = cnt[n];
    float v = sums[n * 16 + o] / fmaxf(c, 1.f);
    float a = conv_b[o];
    #pragma unroll
    for (int i = 0; i < F_IN; i++) a = fmaf(xsh[ln * 16 + i], rw[o * 16 + i], a);
    const float h = fmaxf(v + a, 0.f);

    const int b = batch[n];
    atomicMax(&gmax[b * 16 + o], __float_as_uint(h));  // h>=0: uint order == float order
    atomicAdd(&gsum[b * 16 + o], h);
    if (o == 0) atomicAdd(&gcnt[b], 1.f);
}

// One thread per graph; single block.
__global__ __launch_bounds__(256) void pool_kernel(
    const unsigned int* __restrict__ gmax, const float* __restrict__ gsum,
    const float* __restrict__ gcnt,
    const float* __restrict__ lin1_w, const float* __restrict__ lin1_b,
    const float* __restrict__ lin2_w, const float* __restrict__ lin2_b,
    float* __restrict__ out)
{
    const int g = threadIdx.x;   // 256 graphs

    float pooled[2 * EMB];
    #pragma unroll
    for (int o = 0; o < EMB; o++) pooled[o] = __uint_as_float(gmax[g * 16 + o]);
    const float c = fmaxf(gcnt[g], 1.f);
    #pragma unroll
    for (int o = 0; o < EMB; o++) pooled[EMB + o] = gsum[g * 16 + o] / c;

    float acc = lin2_b[0];
    #pragma unroll
    for (int j = 0; j < EMB; j++) {
        float a = lin1_b[j];
        #pragma unroll
        for (int cidx = 0; cidx < 2 * EMB; cidx++)
            a = fmaf(pooled[cidx], lin1_w[j * 32 + cidx], a);
        acc = fmaf(fmaxf(a, 0.f), lin2_w[j], acc);
    }
    out[g] = acc;
}

extern "C" void kernel_launch(void* const* d_in, const int* in_sizes, int n_in,
                              void* d_out, int out_size, void* d_ws, size_t ws_size,
                              hipStream_t stream) {
    const float* x      = (const float*)d_in[0];
    const int*   ei     = (const int*)d_in[1];
    const float* ea     = (const float*)d_in[2];
    const int*   batch  = (const int*)d_in[3];
    const float* nn1_w  = (const float*)d_in[4];
    const float* nn1_b  = (const float*)d_in[5];
    const float* root_w = (const float*)d_in[6];
    const float* conv_b = (const float*)d_in[7];
    const float* lin1_w = (const float*)d_in[8];
    const float* lin1_b = (const float*)d_in[9];
    const float* lin2_w = (const float*)d_in[10];
    const float* lin2_b = (const float*)d_in[11];
    float* out = (float*)d_out;

    float*        sums = (float*)d_ws;
    float*        cnt  = sums + (size_t)NUM_NODES * EMB;
    unsigned int* gmax = (unsigned int*)(cnt + NUM_NODES);
    float*        gsum = (float*)(gmax + NUM_GRAPHS * EMB);
    float*        gcnt = gsum + NUM_GRAPHS * EMB;

    const size_t zero_bytes = sizeof(float) *
        ((size_t)NUM_NODES * EMB + NUM_NODES + 2 * NUM_GRAPHS * EMB + NUM_GRAPHS);
    hipMemsetAsync(d_ws, 0, zero_bytes, stream);

    edge_kernel<<<NUM_EDGES / 16, 256, 0, stream>>>(x, ei, ea, nn1_w, nn1_b, sums, cnt);
    node_kernel<<<(NUM_NODES * EMB) / 256, 256, 0, stream>>>(
        x, batch, root_w, conv_b, sums, cnt, gmax, gsum, gcnt);
    pool_kernel<<<1, 256, 0, stream>>>(gmax, gsum, gcnt,
                                       lin1_w, lin1_b, lin2_w, lin2_b, out);
}

// Round 2
// 193.738 us; speedup vs baseline: 2.2623x; 2.2623x over previous
//
#include <hip/hip_runtime.h>

#define NUM_NODES 100000
#define NUM_EDGES 400000
#define F_IN 16
#define F_EDGE 8
#define EMB 16
#define NUM_GRAPHS 256

// ---------------------------------------------------------------------------
// Workspace layout (zeroed by hipMemsetAsync each launch):
//   sums : NUM_NODES*EMB f32  (scatter-sum of edge messages)
//   cnt  : NUM_NODES     f32  (incoming-edge counts)
// Pooling uses NO atomics: batch is sorted, so one block per graph reduces
// its contiguous node range found via binary search.
// ---------------------------------------------------------------------------

// One block = 16 edges x 16 output channels. Thread (eL, o) computes
// msg[e][o] = sum_i x[src[e]][i] * relu(b[i*16+o] + sum_k ea[e][k]*W[(i*16+o)][k])
__global__ __launch_bounds__(256) void edge_kernel(
    const float* __restrict__ x, const int* __restrict__ ei,
    const float* __restrict__ ea, const float* __restrict__ nn1_w,
    const float* __restrict__ nn1_b, float* __restrict__ sums,
    float* __restrict__ cnt)
{
    __shared__ float wt[F_IN * EMB * F_EDGE];  // straight copy of nn1_w (8 KB)
    __shared__ float bt[EMB * F_IN];           // bt[o*16+i] = nn1_b[i*16+o]
    __shared__ float xs[16 * F_IN];
    __shared__ float eas[16 * F_EDGE];

    const int tid = threadIdx.x;
    const int eL  = tid >> 4;
    const int o   = tid & 15;
    const int e   = blockIdx.x * 16 + eL;      // grid exact: 400000/16 = 25000

    #pragma unroll
    for (int t = tid; t < F_IN * EMB * F_EDGE; t += 256) wt[t] = nn1_w[t];
    {
        int i = tid >> 4, oo = tid & 15;
        bt[oo * 16 + i] = nn1_b[tid];          // tid = i*16+oo
    }

    const int src = ei[e];
    const int dst = ei[NUM_EDGES + e];

    xs[eL * 16 + o] = x[src * 16 + o];
    if (o < F_EDGE) eas[eL * F_EDGE + o] = ea[e * F_EDGE + o];
    __syncthreads();

    const float4 ea0 = *(const float4*)&eas[eL * F_EDGE];
    const float4 ea1 = *(const float4*)&eas[eL * F_EDGE + 4];

    float xr[F_IN];
    #pragma unroll
    for (int i = 0; i < F_IN; i++) xr[i] = xs[eL * 16 + i];
    float br[F_IN];
    #pragma unroll
    for (int i = 0; i < F_IN; i++) br[i] = bt[o * 16 + i];

    float acc = 0.f;
    #pragma unroll
    for (int i = 0; i < F_IN; i++) {
        const float4* wr = (const float4*)&wt[(i * 16 + o) * F_EDGE];
        const float4 w0 = wr[0];
        const float4 w1 = wr[1];
        float w = br[i];
        w = fmaf(ea0.x, w0.x, w); w = fmaf(ea0.y, w0.y, w);
        w = fmaf(ea0.z, w0.z, w); w = fmaf(ea0.w, w0.w, w);
        w = fmaf(ea1.x, w1.x, w); w = fmaf(ea1.y, w1.y, w);
        w = fmaf(ea1.z, w1.z, w); w = fmaf(ea1.w, w1.w, w);
        w = fmaxf(w, 0.f);
        acc = fmaf(xr[i], w, acc);
    }

    atomicAdd(&sums[dst * 16 + o], acc);
    if (o == 0) atomicAdd(&cnt[dst], 1.f);
}

// One block per graph. Computes h = relu(agg + x@root_w^T + conv_b) for its
// contiguous node range, reduces max/sum, and applies the lin1/lin2 head.
// Thread layout: (j = tid>>4) node-lane, (o = tid&15) channel.
__global__ __launch_bounds__(256) void pool_kernel(
    const float* __restrict__ x, const int* __restrict__ batch,
    const float* __restrict__ root_w, const float* __restrict__ conv_b,
    const float* __restrict__ sums, const float* __restrict__ cnt,
    const float* __restrict__ lin1_w, const float* __restrict__ lin1_b,
    const float* __restrict__ lin2_w, const float* __restrict__ lin2_b,
    float* __restrict__ out)
{
    __shared__ int   srange[2];
    __shared__ float rwT[EMB * F_IN];   // rwT[i*16+o] = root_w[o*16+i] (conflict-free reads)
    __shared__ float xsh[256];          // 16 nodes x 16 features
    __shared__ float ssh[256];          // 16 nodes x 16 message-sums
    __shared__ float csh[16];           // 16 node counts
    __shared__ float redmax[256];
    __shared__ float redsum[256];
    __shared__ float pl[2 * EMB];
    __shared__ float h2s[EMB];

    const int g   = blockIdx.x;
    const int tid = threadIdx.x;
    const int j   = tid >> 4;
    const int o   = tid & 15;

    rwT[o * 16 + j] = root_w[tid];      // tid = o_w*16+i_w -> transpose

    if (tid < 2) {
        const int target = g + tid;     // first n with batch[n] >= target
        int lo = 0, hi = NUM_NODES;
        while (lo < hi) {
            int mid = (lo + hi) >> 1;
            if (batch[mid] < target) lo = mid + 1; else hi = mid;
        }
        srange[tid] = lo;
    }
    __syncthreads();
    const int start = srange[0];
    const int end   = srange[1];

    const float cb = conv_b[o];
    float amax = 0.f;   // h >= 0, so 0 is a valid identity for max
    float asum = 0.f;

    for (int base = start; base < end; base += 16) {
        __syncthreads();
        const int idx = base * 16 + tid;
        xsh[tid] = (idx < NUM_NODES * 16) ? x[idx]    : 0.f;
        ssh[tid] = (idx < NUM_NODES * 16) ? sums[idx] : 0.f;
        if (tid < 16) {
            const int n = base + tid;
            csh[tid] = (n < NUM_NODES) ? cnt[n] : 1.f;
        }
        __syncthreads();

        const int n = base + j;
        if (n < end) {
            float a = cb + ssh[j * 16 + o] / fmaxf(csh[j], 1.f);
            #pragma unroll
            for (int i = 0; i < F_IN; i++)
                a = fmaf(xsh[j * 16 + i], rwT[i * 16 + o], a);
            const float h = fmaxf(a, 0.f);
            amax = fmaxf(amax, h);
            asum += h;
        }
    }

    redmax[tid] = amax;
    redsum[tid] = asum;
    __syncthreads();
    #pragma unroll
    for (int s = 128; s >= 16; s >>= 1) {
        if (tid < s) {
            redmax[tid] = fmaxf(redmax[tid], redmax[tid + s]);
            redsum[tid] += redsum[tid + s];
        }
        __syncthreads();
    }

    if (tid < 16) {
        pl[tid]       = redmax[tid];
        pl[16 + tid]  = redsum[tid] / fmaxf((float)(end - start), 1.f);
    }
    __syncthreads();

    if (tid < 16) {
        float a = lin1_b[tid];
        #pragma unroll
        for (int c = 0; c < 2 * EMB; c++)
            a = fmaf(pl[c], lin1_w[tid * 32 + c], a);
        h2s[tid] = fmaxf(a, 0.f);
    }
    __syncthreads();

    if (tid == 0) {
        float acc = lin2_b[0];
        #pragma unroll
        for (int k = 0; k < EMB; k++)
            acc = fmaf(h2s[k], lin2_w[k], acc);
        out[g] = acc;
    }
}

extern "C" void kernel_launch(void* const* d_in, const int* in_sizes, int n_in,
                              void* d_out, int out_size, void* d_ws, size_t ws_size,
                              hipStream_t stream) {
    const float* x      = (const float*)d_in[0];
    const int*   ei     = (const int*)d_in[1];
    const float* ea     = (const float*)d_in[2];
    const int*   batch  = (const int*)d_in[3];
    const float* nn1_w  = (const float*)d_in[4];
    const float* nn1_b  = (const float*)d_in[5];
    const float* root_w = (const float*)d_in[6];
    const float* conv_b = (const float*)d_in[7];
    const float* lin1_w = (const float*)d_in[8];
    const float* lin1_b = (const float*)d_in[9];
    const float* lin2_w = (const float*)d_in[10];
    const float* lin2_b = (const float*)d_in[11];
    float* out = (float*)d_out;

    float* sums = (float*)d_ws;
    float* cnt  = sums + (size_t)NUM_NODES * EMB;

    const size_t zero_bytes = sizeof(float) * ((size_t)NUM_NODES * EMB + NUM_NODES);
    hipMemsetAsync(d_ws, 0, zero_bytes, stream);

    edge_kernel<<<NUM_EDGES / 16, 256, 0, stream>>>(x, ei, ea, nn1_w, nn1_b, sums, cnt);
    pool_kernel<<<NUM_GRAPHS, 256, 0, stream>>>(
        x, batch, root_w, conv_b, sums, cnt,
        lin1_w, lin1_b, lin2_w, lin2_b, out);
}

// Round 3
// 175.806 us; speedup vs baseline: 2.4930x; 1.1020x over previous
//
#include <hip/hip_runtime.h>

#define NUM_NODES 100000
#define NUM_EDGES 400000
#define F_IN 16
#define F_EDGE 8
#define EMB 16
#define NUM_GRAPHS 256

#define EDGE_TILES 5                                   // 32-edge tiles per block
#define EDGE_BLOCKS (NUM_EDGES / (32 * EDGE_TILES))    // 2500

// ---------------------------------------------------------------------------
// Workspace (zeroed each launch):
//   sums : NUM_NODES*EMB f32, cnt : NUM_NODES f32,
//   gmax : NUM_GRAPHS*EMB u32 (float bits, h>=0 so uint order == float order),
//   gsum : NUM_GRAPHS*EMB f32, gcnt : NUM_GRAPHS f32
// ---------------------------------------------------------------------------

// Block = 256 threads (eL 0..15, o 0..15), tile = 32 edges: thread handles
// edges (tile+eL) and (tile+16+eL), sharing one weight read per i.
// LDS layouts padded so all hot reads are <=2-way (free) on 32 banks:
//   wtp row stride 12 dwords: first-dword bank = 12*o mod 32 -> 2-way
//   btp stride 20: bank 20*o mod 32 -> 2-way, 16B-aligned for b128
__global__ __launch_bounds__(256) void edge_kernel(
    const float* __restrict__ x, const int* __restrict__ ei,
    const float* __restrict__ ea, const float* __restrict__ nn1_w,
    const float* __restrict__ nn1_b, float* __restrict__ sums,
    float* __restrict__ cnt)
{
    __shared__ float wtp[256 * 12];   // row r=(i*16+o): 8 weights + 4 pad
    __shared__ float btp[16 * 20];    // btp[o*20+i]
    __shared__ float xs[32 * 16];     // x rows of the tile's 32 src nodes
    __shared__ float eas[32 * 8];
    __shared__ int   srcs[32];
    __shared__ int   dsts[32];

    const int tid = threadIdx.x;
    const int eL  = tid >> 4;
    const int o   = tid & 15;

    for (int t = tid; t < F_IN * EMB * F_EDGE; t += 256)
        wtp[(t >> 3) * 12 + (t & 7)] = nn1_w[t];
    // nn1_b[tid], tid = i*16+o  ->  btp[o*20+i]
    btp[(tid & 15) * 20 + (tid >> 4)] = nn1_b[tid];
    __syncthreads();

    float br[F_IN];
    #pragma unroll
    for (int r = 0; r < 4; r++) {
        const float4 b4 = *(const float4*)&btp[o * 20 + 4 * r];
        br[4 * r + 0] = b4.x; br[4 * r + 1] = b4.y;
        br[4 * r + 2] = b4.z; br[4 * r + 3] = b4.w;
    }

    for (int t = 0; t < EDGE_TILES; t++) {
        const int e0 = (blockIdx.x * EDGE_TILES + t) * 32;

        __syncthreads();   // previous tile's LDS fully consumed
        if (tid < 32)      srcs[tid]      = ei[e0 + tid];
        else if (tid < 64) dsts[tid - 32] = ei[NUM_EDGES + e0 + tid - 32];
        eas[tid] = ea[e0 * 8 + tid];       // 32 edges x 8 attrs, coalesced
        __syncthreads();   // srcs ready
        xs[tid]       = x[srcs[eL]      * 16 + o];
        xs[256 + tid] = x[srcs[16 + eL] * 16 + o];
        __syncthreads();   // xs/eas ready

        const float4 a00 = *(const float4*)&eas[eL * 8];
        const float4 a01 = *(const float4*)&eas[eL * 8 + 4];
        const float4 a10 = *(const float4*)&eas[(16 + eL) * 8];
        const float4 a11 = *(const float4*)&eas[(16 + eL) * 8 + 4];

        float xr0[F_IN], xr1[F_IN];
        #pragma unroll
        for (int r = 0; r < 4; r++) {
            const float4 v0 = *(const float4*)&xs[eL * 16 + 4 * r];
            const float4 v1 = *(const float4*)&xs[(16 + eL) * 16 + 4 * r];
            xr0[4 * r + 0] = v0.x; xr0[4 * r + 1] = v0.y;
            xr0[4 * r + 2] = v0.z; xr0[4 * r + 3] = v0.w;
            xr1[4 * r + 0] = v1.x; xr1[4 * r + 1] = v1.y;
            xr1[4 * r + 2] = v1.z; xr1[4 * r + 3] = v1.w;
        }

        float acc0 = 0.f, acc1 = 0.f;
        #pragma unroll
        for (int i = 0; i < F_IN; i++) {
            const float* wr = &wtp[(i * 16 + o) * 12];
            const float4 w0 = *(const float4*)wr;
            const float4 w1 = *(const float4*)(wr + 4);
            float u = br[i];
            u = fmaf(a00.x, w0.x, u); u = fmaf(a00.y, w0.y, u);
            u = fmaf(a00.z, w0.z, u); u = fmaf(a00.w, w0.w, u);
            u = fmaf(a01.x, w1.x, u); u = fmaf(a01.y, w1.y, u);
            u = fmaf(a01.z, w1.z, u); u = fmaf(a01.w, w1.w, u);
            acc0 = fmaf(xr0[i], fmaxf(u, 0.f), acc0);
            float v = br[i];
            v = fmaf(a10.x, w0.x, v); v = fmaf(a10.y, w0.y, v);
            v = fmaf(a10.z, w0.z, v); v = fmaf(a10.w, w0.w, v);
            v = fmaf(a11.x, w1.x, v); v = fmaf(a11.y, w1.y, v);
            v = fmaf(a11.z, w1.z, v); v = fmaf(a11.w, w1.w, v);
            acc1 = fmaf(xr1[i], fmaxf(v, 0.f), acc1);
        }

        atomicAdd(&sums[dsts[eL] * 16 + o],      acc0);
        atomicAdd(&sums[dsts[16 + eL] * 16 + o], acc1);
        if (o == 0) {
            atomicAdd(&cnt[dsts[eL]],      1.f);
            atomicAdd(&cnt[dsts[16 + eL]], 1.f);
        }
    }
}

// P1: one block per 16 nodes (6250 blocks). Computes h = relu(agg + x@root_w^T
// + conv_b), then flushes per-block SEGMENTED max/sum/count with a handful of
// low-contention atomics (blocks are 16 nodes; graphs ~390 -> 1-2 segments).
__global__ __launch_bounds__(256) void node_kernel(
    const float* __restrict__ x, const int* __restrict__ batch,
    const float* __restrict__ root_w, const float* __restrict__ conv_b,
    const float* __restrict__ sums, const float* __restrict__ cnt,
    unsigned int* __restrict__ gmax, float* __restrict__ gsum,
    float* __restrict__ gcnt)
{
    __shared__ float rwT[256];   // rwT[i*16+o] = root_w[o*16+i]
    __shared__ float xsh[256];
    __shared__ float ssh[256];
    __shared__ float csh[16];
    __shared__ int   bsh[16];
    __shared__ float hsh[256];

    const int tid = threadIdx.x;
    const int j   = tid >> 4;
    const int o   = tid & 15;
    const int n0  = blockIdx.x * 16;   // 6250*16 = 100000 exact

    rwT[(tid & 15) * 16 + (tid >> 4)] = root_w[tid];
    xsh[tid] = x[n0 * 16 + tid];
    ssh[tid] = sums[n0 * 16 + tid];
    if (tid < 16)      csh[tid]      = cnt[n0 + tid];
    else if (tid < 32) bsh[tid - 16] = batch[n0 + tid - 16];
    __syncthreads();

    float a = conv_b[o] + ssh[j * 16 + o] / fmaxf(csh[j], 1.f);
    #pragma unroll
    for (int i = 0; i < F_IN; i++)
        a = fmaf(xsh[j * 16 + i], rwT[i * 16 + o], a);
    hsh[tid] = fmaxf(a, 0.f);
    __syncthreads();

    if (tid < 16) {          // thread per channel: segmented flush over 16 nodes
        int cur = bsh[0]; float m = 0.f, s = 0.f;
        for (int jj = 0; jj < 16; jj++) {
            if (bsh[jj] != cur) {
                atomicMax(&gmax[cur * 16 + tid], __float_as_uint(m));
                atomicAdd(&gsum[cur * 16 + tid], s);
                cur = bsh[jj]; m = 0.f; s = 0.f;
            }
            const float h = hsh[jj * 16 + tid];
            m = fmaxf(m, h); s += h;
        }
        atomicMax(&gmax[cur * 16 + tid], __float_as_uint(m));
        atomicAdd(&gsum[cur * 16 + tid], s);
    } else if (tid == 16) {  // counts
        int cur = bsh[0]; float c = 0.f;
        for (int jj = 0; jj < 16; jj++) {
            if (bsh[jj] != cur) { atomicAdd(&gcnt[cur], c); cur = bsh[jj]; c = 0.f; }
            c += 1.f;
        }
        atomicAdd(&gcnt[cur], c);
    }
}

// P2: head MLP, one thread per graph, single block.
__global__ __launch_bounds__(256) void head_kernel(
    const unsigned int* __restrict__ gmax, const float* __restrict__ gsum,
    const float* __restrict__ gcnt,
    const float* __restrict__ lin1_w, const float* __restrict__ lin1_b,
    const float* __restrict__ lin2_w, const float* __restrict__ lin2_b,
    float* __restrict__ out)
{
    const int g = threadIdx.x;

    float pooled[2 * EMB];
    #pragma unroll
    for (int o = 0; o < EMB; o++) pooled[o] = __uint_as_float(gmax[g * 16 + o]);
    const float c = fmaxf(gcnt[g], 1.f);
    #pragma unroll
    for (int o = 0; o < EMB; o++) pooled[EMB + o] = gsum[g * 16 + o] / c;

    float acc = lin2_b[0];
    #pragma unroll
    for (int k = 0; k < EMB; k++) {
        float a = lin1_b[k];
        #pragma unroll
        for (int cc = 0; cc < 2 * EMB; cc++)
            a = fmaf(pooled[cc], lin1_w[k * 32 + cc], a);
        acc = fmaf(fmaxf(a, 0.f), lin2_w[k], acc);
    }
    out[g] = acc;
}

extern "C" void kernel_launch(void* const* d_in, const int* in_sizes, int n_in,
                              void* d_out, int out_size, void* d_ws, size_t ws_size,
                              hipStream_t stream) {
    const float* x      = (const float*)d_in[0];
    const int*   ei     = (const int*)d_in[1];
    const float* ea     = (const float*)d_in[2];
    const int*   batch  = (const int*)d_in[3];
    const float* nn1_w  = (const float*)d_in[4];
    const float* nn1_b  = (const float*)d_in[5];
    const float* root_w = (const float*)d_in[6];
    const float* conv_b = (const float*)d_in[7];
    const float* lin1_w = (const float*)d_in[8];
    const float* lin1_b = (const float*)d_in[9];
    const float* lin2_w = (const float*)d_in[10];
    const float* lin2_b = (const float*)d_in[11];
    float* out = (float*)d_out;

    float*        sums = (float*)d_ws;
    float*        cnt  = sums + (size_t)NUM_NODES * EMB;
    unsigned int* gmax = (unsigned int*)(cnt + NUM_NODES);
    float*        gsum = (float*)(gmax + NUM_GRAPHS * EMB);
    float*        gcnt = gsum + NUM_GRAPHS * EMB;

    const size_t zero_bytes = sizeof(float) *
        ((size_t)NUM_NODES * EMB + NUM_NODES + 2 * NUM_GRAPHS * EMB + NUM_GRAPHS);
    hipMemsetAsync(d_ws, 0, zero_bytes, stream);

    edge_kernel<<<EDGE_BLOCKS, 256, 0, stream>>>(x, ei, ea, nn1_w, nn1_b, sums, cnt);
    node_kernel<<<NUM_NODES / 16, 256, 0, stream>>>(
        x, batch, root_w, conv_b, sums, cnt, gmax, gsum, gcnt);
    head_kernel<<<1, 256, 0, stream>>>(gmax, gsum, gcnt,
                                       lin1_w, lin1_b, lin2_w, lin2_b, out);
}

// Round 4
// 165.622 us; speedup vs baseline: 2.6463x; 1.0615x over previous
//
#include <hip/hip_runtime.h>

#define NUM_NODES 100000
#define NUM_EDGES 400000
#define F_IN 16
#define F_EDGE 8
#define EMB 16
#define NUM_GRAPHS 256

#define EDGE_TILES 5                                   // 32-edge tiles per block
#define EDGE_BLOCKS (NUM_EDGES / (32 * EDGE_TILES))    // 2500

#define NPB 128                                        // nodes per node_kernel block
#define NODE_BLOCKS ((NUM_NODES + NPB - 1) / NPB)      // 782

// ---------------------------------------------------------------------------
// Workspace (zeroed each launch):
//   sums : NUM_NODES*EMB f32, cnt : NUM_NODES f32,
//   gmax : NUM_GRAPHS*EMB u32 (float bits, h>=0 so uint order == float order),
//   gsum : NUM_GRAPHS*EMB f32, gcnt : NUM_GRAPHS f32
// ---------------------------------------------------------------------------

// Block = 256 threads (eL 0..15, o 0..15); tile = 32 edges; thread handles
// edges (tile+eL) and (tile+16+eL) sharing one LDS weight read per i.
// NO barriers inside the tile loop: LDS holds only the (read-only) weights,
// all per-tile data comes from global (o-group lanes broadcast-load the same
// lines; x/ea are L2-resident). Fire-and-forget atomics never get drained.
// LDS pads: wtp row stride 12 -> bank 12*o mod 32 (2-way = free);
//           btp stride 20 -> 2-way, 16B-aligned.
__global__ __launch_bounds__(256) void edge_kernel(
    const float* __restrict__ x, const int* __restrict__ ei,
    const float* __restrict__ ea, const float* __restrict__ nn1_w,
    const float* __restrict__ nn1_b, float* __restrict__ sums,
    float* __restrict__ cnt)
{
    __shared__ float wtp[256 * 12];   // row r=(i*16+o): 8 weights + 4 pad
    __shared__ float btp[16 * 20];    // btp[o*20+i]

    const int tid = threadIdx.x;
    const int eL  = tid >> 4;
    const int o   = tid & 15;

    #pragma unroll
    for (int t = tid; t < F_IN * EMB * F_EDGE; t += 256)
        wtp[(t >> 3) * 12 + (t & 7)] = nn1_w[t];
    btp[(tid & 15) * 20 + (tid >> 4)] = nn1_b[tid];   // tid = i*16+o
    __syncthreads();                                   // the ONLY barrier

    float br[F_IN];
    #pragma unroll
    for (int r = 0; r < 4; r++) {
        const float4 b4 = *(const float4*)&btp[o * 20 + 4 * r];
        br[4 * r + 0] = b4.x; br[4 * r + 1] = b4.y;
        br[4 * r + 2] = b4.z; br[4 * r + 3] = b4.w;
    }

    for (int t = 0; t < EDGE_TILES; t++) {
        const int e0 = (blockIdx.x * EDGE_TILES + t) * 32;
        const int eA = e0 + eL;
        const int eB = e0 + 16 + eL;

        const int srcA = ei[eA];
        const int srcB = ei[eB];
        const int dstA = ei[NUM_EDGES + eA];
        const int dstB = ei[NUM_EDGES + eB];

        const float4 a00 = *(const float4*)&ea[eA * 8];
        const float4 a01 = *(const float4*)&ea[eA * 8 + 4];
        const float4 a10 = *(const float4*)&ea[eB * 8];
        const float4 a11 = *(const float4*)&ea[eB * 8 + 4];

        float xr0[F_IN], xr1[F_IN];
        #pragma unroll
        for (int r = 0; r < 4; r++) {
            const float4 v0 = *(const float4*)&x[srcA * 16 + 4 * r];
            const float4 v1 = *(const float4*)&x[srcB * 16 + 4 * r];
            xr0[4 * r + 0] = v0.x; xr0[4 * r + 1] = v0.y;
            xr0[4 * r + 2] = v0.z; xr0[4 * r + 3] = v0.w;
            xr1[4 * r + 0] = v1.x; xr1[4 * r + 1] = v1.y;
            xr1[4 * r + 2] = v1.z; xr1[4 * r + 3] = v1.w;
        }

        float acc0 = 0.f, acc1 = 0.f;
        #pragma unroll
        for (int i = 0; i < F_IN; i++) {
            const float* wr = &wtp[(i * 16 + o) * 12];
            const float4 w0 = *(const float4*)wr;
            const float4 w1 = *(const float4*)(wr + 4);
            float u = br[i];
            u = fmaf(a00.x, w0.x, u); u = fmaf(a00.y, w0.y, u);
            u = fmaf(a00.z, w0.z, u); u = fmaf(a00.w, w0.w, u);
            u = fmaf(a01.x, w1.x, u); u = fmaf(a01.y, w1.y, u);
            u = fmaf(a01.z, w1.z, u); u = fmaf(a01.w, w1.w, u);
            acc0 = fmaf(xr0[i], fmaxf(u, 0.f), acc0);
            float v = br[i];
            v = fmaf(a10.x, w0.x, v); v = fmaf(a10.y, w0.y, v);
            v = fmaf(a10.z, w0.z, v); v = fmaf(a10.w, w0.w, v);
            v = fmaf(a11.x, w1.x, v); v = fmaf(a11.y, w1.y, v);
            v = fmaf(a11.z, w1.z, v); v = fmaf(a11.w, w1.w, v);
            acc1 = fmaf(xr1[i], fmaxf(v, 0.f), acc1);
        }

        atomicAdd(&sums[dstA * 16 + o], acc0);
        atomicAdd(&sums[dstB * 16 + o], acc1);
        if (o == 0) {
            atomicAdd(&cnt[dstA], 1.f);
            atomicAdd(&cnt[dstB], 1.f);
        }
    }
}

// One block per 128 nodes. Computes h = relu(agg + x@root_w^T + conv_b) in
// 16-node sub-tiles; 16 flusher threads carry per-channel (max,sum,count)
// accumulators in REGISTERS across sub-tiles, hitting global atomics only on
// graph-boundary or block-end (~1-2 flushes/block -> ~64 same-line ops/graph).
__global__ __launch_bounds__(256) void node_kernel(
    const float* __restrict__ x, const int* __restrict__ batch,
    const float* __restrict__ root_w, const float* __restrict__ conv_b,
    const float* __restrict__ sums, const float* __restrict__ cnt,
    unsigned int* __restrict__ gmax, float* __restrict__ gsum,
    float* __restrict__ gcnt)
{
    __shared__ float rwT[256];   // rwT[i*16+o] = root_w[o*16+i]
    __shared__ float xsh[256];
    __shared__ float ssh[256];
    __shared__ float csh[16];
    __shared__ int   bsh[16];
    __shared__ float hsh[256];

    const int tid = threadIdx.x;
    const int j   = tid >> 4;
    const int o   = tid & 15;
    const int n0  = blockIdx.x * NPB;

    rwT[(tid & 15) * 16 + (tid >> 4)] = root_w[tid];
    const float cb = conv_b[o];

    // flusher state (threads 0..15; lockstep, same wave)
    int   curg = batch[n0];      // n0 < NUM_NODES for all 782 blocks
    float am = 0.f, asum = 0.f, ac = 0.f;

    for (int s0 = 0; s0 < NPB; s0 += 16) {
        const int base = n0 + s0;
        const int idx  = base * 16 + tid;
        const bool v   = (idx < NUM_NODES * 16);
        const float xv = v ? x[idx]    : 0.f;
        const float sv = v ? sums[idx] : 0.f;
        float cv = 1.f; int bv = -1;
        if (tid < 16) {
            const int n = base + tid;
            if (n < NUM_NODES) { cv = cnt[n]; bv = batch[n]; }
        }
        __syncthreads();   // prev sub-tile's hsh/bsh fully consumed
        xsh[tid] = xv; ssh[tid] = sv;
        if (tid < 16) { csh[tid] = cv; bsh[tid] = bv; }
        __syncthreads();

        float a = cb + ssh[j * 16 + o] / fmaxf(csh[j], 1.f);
        #pragma unroll
        for (int i = 0; i < F_IN; i++)
            a = fmaf(xsh[j * 16 + i], rwT[i * 16 + o], a);
        hsh[tid] = fmaxf(a, 0.f);
        __syncthreads();   // hsh ready

        if (tid < 16) {
            #pragma unroll 1
            for (int jj = 0; jj < 16; jj++) {
                const int g = bsh[jj];
                if (g < 0) break;              // past last node
                if (g != curg) {
                    atomicMax(&gmax[curg * 16 + o], __float_as_uint(am));
                    atomicAdd(&gsum[curg * 16 + o], asum);
                    if (o == 0) atomicAdd(&gcnt[curg], ac);
                    am = 0.f; asum = 0.f; ac = 0.f; curg = g;
                }
                const float h = hsh[jj * 16 + o];
                am = fmaxf(am, h); asum += h; ac += 1.f;
            }
        }
    }

    if (tid < 16) {   // final flush
        atomicMax(&gmax[curg * 16 + o], __float_as_uint(am));
        atomicAdd(&gsum[curg * 16 + o], asum);
        if (o == 0) atomicAdd(&gcnt[curg], ac);
    }
}

// Head MLP: one thread per graph, single block.
__global__ __launch_bounds__(256) void head_kernel(
    const unsigned int* __restrict__ gmax, const float* __restrict__ gsum,
    const float* __restrict__ gcnt,
    const float* __restrict__ lin1_w, const float* __restrict__ lin1_b,
    const float* __restrict__ lin2_w, const float* __restrict__ lin2_b,
    float* __restrict__ out)
{
    const int g = threadIdx.x;

    float pooled[2 * EMB];
    #pragma unroll
    for (int o = 0; o < EMB; o++) pooled[o] = __uint_as_float(gmax[g * 16 + o]);
    const float c = fmaxf(gcnt[g], 1.f);
    #pragma unroll
    for (int o = 0; o < EMB; o++) pooled[EMB + o] = gsum[g * 16 + o] / c;

    float acc = lin2_b[0];
    #pragma unroll
    for (int k = 0; k < EMB; k++) {
        float a = lin1_b[k];
        #pragma unroll
        for (int cc = 0; cc < 2 * EMB; cc++)
            a = fmaf(pooled[cc], lin1_w[k * 32 + cc], a);
        acc = fmaf(fmaxf(a, 0.f), lin2_w[k], acc);
    }
    out[g] = acc;
}

extern "C" void kernel_launch(void* const* d_in, const int* in_sizes, int n_in,
                              void* d_out, int out_size, void* d_ws, size_t ws_size,
                              hipStream_t stream) {
    const float* x      = (const float*)d_in[0];
    const int*   ei     = (const int*)d_in[1];
    const float* ea     = (const float*)d_in[2];
    const int*   batch  = (const int*)d_in[3];
    const float* nn1_w  = (const float*)d_in[4];
    const float* nn1_b  = (const float*)d_in[5];
    const float* root_w = (const float*)d_in[6];
    const float* conv_b = (const float*)d_in[7];
    const float* lin1_w = (const float*)d_in[8];
    const float* lin1_b = (const float*)d_in[9];
    const float* lin2_w = (const float*)d_in[10];
    const float* lin2_b = (const float*)d_in[11];
    float* out = (float*)d_out;

    float*        sums = (float*)d_ws;
    float*        cnt  = sums + (size_t)NUM_NODES * EMB;
    unsigned int* gmax = (unsigned int*)(cnt + NUM_NODES);
    float*        gsum = (float*)(gmax + NUM_GRAPHS * EMB);
    float*        gcnt = gsum + NUM_GRAPHS * EMB;

    const size_t zero_bytes = sizeof(float) *
        ((size_t)NUM_NODES * EMB + NUM_NODES + 2 * NUM_GRAPHS * EMB + NUM_GRAPHS);
    hipMemsetAsync(d_ws, 0, zero_bytes, stream);

    edge_kernel<<<EDGE_BLOCKS, 256, 0, stream>>>(x, ei, ea, nn1_w, nn1_b, sums, cnt);
    node_kernel<<<NODE_BLOCKS, 256, 0, stream>>>(
        x, batch, root_w, conv_b, sums, cnt, gmax, gsum, gcnt);
    head_kernel<<<1, 256, 0, stream>>>(gmax, gsum, gcnt,
                                       lin1_w, lin1_b, lin2_w, lin2_b, out);
}